// Round 13
// baseline (26.270 us; speedup 1.0000x reference)
//
#include <hip/hip_runtime.h>
#include <hip/hip_fp16.h>

#define TILE 16

typedef __fp16 h2f __attribute__((ext_vector_type(2)));

union H2U { h2f h; unsigned u; __half2 hh; };

__device__ __forceinline__ h2f u2h(unsigned u) { H2U t; t.u = u; return t.h; }

__device__ __forceinline__ unsigned pack_h2(float a, float b) {
    H2U t; t.hh = __halves2half2(__float2half_rn(a), __float2half_rn(b));
    return t.u;
}

// dot2: acc += a.x*b.x + a.y*b.y (f16 mul, f32 acc) — V_DOT2_F32_F16
__device__ __forceinline__ float fdot2(h2f a, h2f b, float acc) {
#if __has_builtin(__builtin_amdgcn_fdot2)
    return __builtin_amdgcn_fdot2(a, b, acc, false);
#else
    return acc + (float)a.x * (float)b.x + (float)a.y * (float)b.y;
#endif
}

// Encode one KAN input: g=silu(v); knot coord T=(v-g0)*invh; w=frac, si=interval
// slot (0 => out-of-span zero slot; 1..tmax => interval floor(T)).
struct Enc { float g, w; int si; };
__device__ __forceinline__ Enc kan_enc3(float v, float g0, float invh, float tmax) {
    Enc e;
    e.g = v / (1.0f + __expf(-v));
    float T = (v - g0) * invh;
    float U = (T >= 0.0f && T < tmax) ? T : -1.0f;
    float mf = floorf(U);
    e.w = U - mf;          // 0 when out of span
    e.si = (int)mf + 1;    // 0 when out of span
    return e;
}

__device__ __forceinline__ float poly_eval(float4 c, float w) {
    return ((c.w * w + c.z) * w + c.y) * w + c.x;
}

// Piecewise-cubic table entry for interval slot si (si=0 zero slot).
__device__ __forceinline__ float4 spline_poly(const float* __restrict__ sw, float sc,
                                              int ncoef, int si) {
    float4 v = make_float4(0.f, 0.f, 0.f, 0.f);
    if (si > 0) {
        int m = si - 1;
        float W[4];
        #pragma unroll
        for (int j = 0; j < 4; ++j) {
            int c = m - 3 + j;
            W[j] = (c >= 0 && c < ncoef) ? sw[c] * sc : 0.0f;
        }
        const float s6 = 1.0f / 6.0f;
        v.x = (W[0] + 4.0f * W[1] + W[2]) * s6;
        v.y = 3.0f * (W[2] - W[0]) * s6;
        v.z = (3.0f * W[0] - 6.0f * W[1] + 3.0f * W[2]) * s6;
        v.w = (W[3] - W[0] + 3.0f * (W[1] - W[2])) * s6;
    }
    return v;
}

__global__ __launch_bounds__(256) void ZS_MKAN_72121090834671_kernel(
    const float* __restrict__ x,
    const float* __restrict__ base_w1, const float* __restrict__ spline_w1,
    const float* __restrict__ scaler1,
    const float* __restrict__ base_w2, const float* __restrict__ spline_w2,
    const float* __restrict__ scaler2,
    const float* __restrict__ conv_w, const float* __restrict__ conv_b,
    const float* __restrict__ base_w6, const float* __restrict__ spline_w6,
    const float* __restrict__ scaler6,
    float* __restrict__ out)
{
    __shared__ float2  encXg[1200];        // (g,w) per x-halo pixel, 3ch x 20x20
    __shared__ unsigned short encXs[1200]; // si per x-halo pixel
    __shared__ float4  encYg[3][324];      // (g0,w0,g1,w1) layer1-out pairs, 18x18
    __shared__ ushort2 encYs[3][324];      // (si0,si1)
    __shared__ uint4   coefH1[9][10];      // layer1 f16x8: k0{c0..c3}, k1{c0..c3}
    __shared__ uint4   coefH2[9][10];      // layer2 f16x8
    __shared__ float4  coef6[12];          // layer6 f32: 11 intervals + zero slot
    __shared__ float   sbw[2][18];         // base_w1 / base_w2
    __shared__ float   scw[36], scb[3];    // 1x1 conv
    __shared__ float   sb6;

    const int tid = threadIdx.x;
    const int tx0 = blockIdx.x * TILE;
    const int ty0 = blockIdx.y * TILE;
    const int b   = blockIdx.z;

    // ---- build f16 k-pair-packed spline tables for both conv layers ----
    for (int e = tid; e < 180; e += 256) {
        int l = e / 90, r = e % 90, s = r / 10, si = r % 10;
        const float* sw  = l ? spline_w2 : spline_w1;
        const float* scl = l ? scaler2   : scaler1;
        float4 a = spline_poly(sw + s * 6,       scl[s],     6, si);
        float4 c = spline_poly(sw + (9 + s) * 6, scl[9 + s], 6, si);
        uint4 q;
        q.x = pack_h2(a.x, a.y); q.y = pack_h2(a.z, a.w);
        q.z = pack_h2(c.x, c.y); q.w = pack_h2(c.z, c.w);
        if (l) coefH2[s][si] = q; else coefH1[s][si] = q;
    }
    if (tid < 12) coef6[tid] = spline_poly(spline_w6, scaler6[0], 8, tid);
    if (tid < 18) { sbw[0][tid] = base_w1[tid]; sbw[1][tid] = base_w2[tid]; }
    if (tid < 36) scw[tid] = conv_w[tid];
    if (tid < 3)  scb[tid] = conv_b[tid];
    if (tid == 0) sb6 = base_w6[0];

    // ---- encode x tile + halo2: 5 explicit slots, loads issued up-front ----
    {
        float xv[5]; int ii[5]; bool val[5];
        #pragma unroll
        for (int p = 0; p < 5; ++p) {
            int i = tid + p * 256;
            val[p] = i < 1200;
            int ic = val[p] ? i : 0;
            int c = ic / 400, r = ic % 400, ly = r / 20, lx = r % 20;
            int gy = ty0 - 2 + ly, gx = tx0 - 2 + lx;
            float xx = 0.0f;
            if (val[p] && (unsigned)gy < 256u && (unsigned)gx < 256u)
                xx = x[((b * 3 + c) * 256 + gy) * 256 + gx];
            xv[p] = xx; ii[p] = ic;
        }
        #pragma unroll
        for (int p = 0; p < 5; ++p) {
            if (val[p]) {
                Enc e = kan_enc3(xv[p], -3.0f, 1.5f, 9.0f);
                encXg[ii[p]] = make_float2(e.g, e.w);
                encXs[ii[p]] = (unsigned short)e.si;
            }
        }
    }
    __syncthreads();

    // ---- layer1 (3ch -> 6ch), 4 positions interleaved per thread ----
    {
        float rb0[9], rb1[9];
        #pragma unroll
        for (int s = 0; s < 9; ++s) { rb0[s] = sbw[0][s]; rb1[s] = sbw[0][9 + s]; }
        int idx[4]; bool vld[4];
        #pragma unroll
        for (int p = 0; p < 4; ++p) {
            int i = tid + p * 256;
            vld[p] = i < 972;
            idx[p] = vld[p] ? i : (i - 256);  // safe duplicate; store masked below
        }
        int bas[4], rr[4], cc[4];
        #pragma unroll
        for (int p = 0; p < 4; ++p) {
            int c = idx[p] / 324, r = idx[p] % 324;
            cc[p] = c; rr[p] = r;
            bas[p] = c * 400 + (r / 18) * 20 + (r % 18);
        }
        float a0[4] = {0.f, 0.f, 0.f, 0.f}, a1[4] = {0.f, 0.f, 0.f, 0.f};
        #pragma unroll
        for (int s = 0; s < 9; ++s) {
            const int off = (s / 3) * 20 + (s % 3);
            #pragma unroll
            for (int p = 0; p < 4; ++p) {
                int qa = bas[p] + off;
                float2 gw = encXg[qa];
                int si = encXs[qa];
                uint4 q = coefH1[s][si];
                float w = gw.y, w2 = w * w;
                h2f ph1 = __builtin_amdgcn_cvt_pkrtz(1.0f, w);
                h2f ph2 = __builtin_amdgcn_cvt_pkrtz(w2, w2 * w);
                a0[p] += gw.x * rb0[s];
                a1[p] += gw.x * rb1[s];
                a0[p] = fdot2(u2h(q.x), ph1, a0[p]); a0[p] = fdot2(u2h(q.y), ph2, a0[p]);
                a1[p] = fdot2(u2h(q.z), ph1, a1[p]); a1[p] = fdot2(u2h(q.w), ph2, a1[p]);
            }
        }
        #pragma unroll
        for (int p = 0; p < 4; ++p) {
            if (vld[p]) {
                int r = rr[p], ly = r / 18, lx = r % 18;
                int gy = ty0 - 1 + ly, gx = tx0 - 1 + lx;
                float v0 = a0[p], v1 = a1[p];
                if (!((unsigned)gy < 256u && (unsigned)gx < 256u)) { v0 = 0.f; v1 = 0.f; }
                Enc e0 = kan_enc3(v0, -3.0f, 1.5f, 9.0f);
                Enc e1 = kan_enc3(v1, -3.0f, 1.5f, 9.0f);
                encYg[cc[p]][r] = make_float4(e0.g, e0.w, e1.g, e1.w);
                encYs[cc[p]][r] = make_ushort2((unsigned short)e0.si, (unsigned short)e1.si);
            }
        }
    }
    __syncthreads();

    // ---- layer2 (6 -> 12), one output pixel per thread ----
    const int ly = tid >> 4, lx = tid & 15;
    float z[12];
    {
        float rb0[9], rb1[9];
        #pragma unroll
        for (int s = 0; s < 9; ++s) { rb0[s] = sbw[1][s]; rb1[s] = sbw[1][9 + s]; }
        const int rbase = ly * 18 + lx;
        #pragma unroll
        for (int c = 0; c < 3; ++c) {    // pair of y-channels (2c, 2c+1)
            float a00 = 0.0f, a01 = 0.0f, a10 = 0.0f, a11 = 0.0f;
            #pragma unroll
            for (int s = 0; s < 9; ++s) {
                int p = rbase + (s / 3) * 18 + (s % 3);
                float4 e = encYg[c][p];
                ushort2 ss = encYs[c][p];
                uint4 q0 = coefH2[s][ss.x];
                uint4 q1 = coefH2[s][ss.y];
                {   // channel h=0
                    float w = e.y, w2 = w * w;
                    h2f p1 = __builtin_amdgcn_cvt_pkrtz(1.0f, w);
                    h2f p2 = __builtin_amdgcn_cvt_pkrtz(w2, w2 * w);
                    a00 += e.x * rb0[s];
                    a01 += e.x * rb1[s];
                    a00 = fdot2(u2h(q0.x), p1, a00); a00 = fdot2(u2h(q0.y), p2, a00);
                    a01 = fdot2(u2h(q0.z), p1, a01); a01 = fdot2(u2h(q0.w), p2, a01);
                }
                {   // channel h=1
                    float w = e.w, w2 = w * w;
                    h2f p1 = __builtin_amdgcn_cvt_pkrtz(1.0f, w);
                    h2f p2 = __builtin_amdgcn_cvt_pkrtz(w2, w2 * w);
                    a10 += e.z * rb0[s];
                    a11 += e.z * rb1[s];
                    a10 = fdot2(u2h(q1.x), p1, a10); a10 = fdot2(u2h(q1.y), p2, a10);
                    a11 = fdot2(u2h(q1.z), p1, a11); a11 = fdot2(u2h(q1.w), p2, a11);
                }
            }
            z[4 * c + 0] = a00; z[4 * c + 1] = a01;
            z[4 * c + 2] = a10; z[4 * c + 3] = a11;
        }
    }

    // ---- 1x1 conv (12->3) + pointwise KAN layer6 (f32) + store ----
    const int gy = ty0 + ly, gx = tx0 + lx;
    #pragma unroll
    for (int o = 0; o < 3; ++o) {
        float v = scb[o];
        #pragma unroll
        for (int c = 0; c < 12; ++c) v += scw[o * 12 + c] * z[c];
        Enc t = kan_enc3(v, -2.2f, 2.5f, 11.0f);
        out[((b * 3 + o) * 256 + gy) * 256 + gx] = t.g * sb6 + poly_eval(coef6[t.si], t.w);
    }
}

extern "C" void kernel_launch(void* const* d_in, const int* in_sizes, int n_in,
                              void* d_out, int out_size, void* d_ws, size_t ws_size,
                              hipStream_t stream) {
    (void)in_sizes; (void)n_in; (void)d_ws; (void)ws_size; (void)out_size;
    const float* x         = (const float*)d_in[0];
    const float* base_w1   = (const float*)d_in[1];
    const float* spline_w1 = (const float*)d_in[2];
    const float* scaler1   = (const float*)d_in[3];
    const float* base_w2   = (const float*)d_in[4];
    const float* spline_w2 = (const float*)d_in[5];
    const float* scaler2   = (const float*)d_in[6];
    const float* conv_w    = (const float*)d_in[7];
    const float* conv_b    = (const float*)d_in[8];
    const float* base_w6   = (const float*)d_in[9];
    const float* spline_w6 = (const float*)d_in[10];
    const float* scaler6   = (const float*)d_in[11];
    float* out = (float*)d_out;

    dim3 grid(256 / TILE, 256 / TILE, 4);
    dim3 block(256);
    ZS_MKAN_72121090834671_kernel<<<grid, block, 0, stream>>>(
        x, base_w1, spline_w1, scaler1, base_w2, spline_w2, scaler2,
        conv_w, conv_b, base_w6, spline_w6, scaler6, out);
}

// Round 14
// 24.002 us; speedup vs baseline: 1.0945x; 1.0945x over previous
//
#include <hip/hip_runtime.h>
#include <hip/hip_fp16.h>

#define TILE 16
#define NT 768

typedef __fp16 h2f __attribute__((ext_vector_type(2)));

union H2U { h2f h; unsigned u; __half2 hh; };

__device__ __forceinline__ h2f u2h(unsigned u) { H2U t; t.u = u; return t.h; }

__device__ __forceinline__ unsigned pack_h2(float a, float b) {
    H2U t; t.hh = __halves2half2(__float2half_rn(a), __float2half_rn(b));
    return t.u;
}

// dot2: acc += a.x*b.x + a.y*b.y (f16 mul, f32 acc) — V_DOT2_F32_F16
__device__ __forceinline__ float fdot2(h2f a, h2f b, float acc) {
#if __has_builtin(__builtin_amdgcn_fdot2)
    return __builtin_amdgcn_fdot2(a, b, acc, false);
#else
    return acc + (float)a.x * (float)b.x + (float)a.y * (float)b.y;
#endif
}

// Encode one KAN input: g=silu(v); knot coord T=(v-g0)*invh; w=frac, si=interval
// slot (0 => out-of-span zero slot; 1..tmax => interval floor(T)).
struct Enc { float g, w; int si; };
__device__ __forceinline__ Enc kan_enc3(float v, float g0, float invh, float tmax) {
    Enc e;
    e.g = v / (1.0f + __expf(-v));
    float T = (v - g0) * invh;
    float U = (T >= 0.0f && T < tmax) ? T : -1.0f;
    float mf = floorf(U);
    e.w = U - mf;          // 0 when out of span
    e.si = (int)mf + 1;    // 0 when out of span
    return e;
}

__device__ __forceinline__ float poly_eval(float4 c, float w) {
    return ((c.w * w + c.z) * w + c.y) * w + c.x;
}

// Piecewise-cubic table entry for interval slot si (si=0 zero slot).
__device__ __forceinline__ float4 spline_poly(const float* __restrict__ sw, float sc,
                                              int ncoef, int si) {
    float4 v = make_float4(0.f, 0.f, 0.f, 0.f);
    if (si > 0) {
        int m = si - 1;
        float W[4];
        #pragma unroll
        for (int j = 0; j < 4; ++j) {
            int c = m - 3 + j;
            W[j] = (c >= 0 && c < ncoef) ? sw[c] * sc : 0.0f;
        }
        const float s6 = 1.0f / 6.0f;
        v.x = (W[0] + 4.0f * W[1] + W[2]) * s6;
        v.y = 3.0f * (W[2] - W[0]) * s6;
        v.z = (3.0f * W[0] - 6.0f * W[1] + 3.0f * W[2]) * s6;
        v.w = (W[3] - W[0] + 3.0f * (W[1] - W[2])) * s6;
    }
    return v;
}

__global__ __launch_bounds__(NT, 6) void ZS_MKAN_72121090834671_kernel(
    const float* __restrict__ x,
    const float* __restrict__ base_w1, const float* __restrict__ spline_w1,
    const float* __restrict__ scaler1,
    const float* __restrict__ base_w2, const float* __restrict__ spline_w2,
    const float* __restrict__ scaler2,
    const float* __restrict__ conv_w, const float* __restrict__ conv_b,
    const float* __restrict__ base_w6, const float* __restrict__ spline_w6,
    const float* __restrict__ scaler6,
    float* __restrict__ out)
{
    __shared__ float2  encXg[1200];        // (g,w) per x-halo pixel, 3ch x 20x20
    __shared__ unsigned short encXs[1200]; // si per x-halo pixel
    __shared__ float4  encYg[3][324];      // (g0,w0,g1,w1) layer1-out pairs, 18x18
    __shared__ ushort2 encYs[3][324];      // (si0,si1)
    __shared__ uint4   coefH1[9][10];      // layer1 f16x8: k0{c0..c3}, k1{c0..c3}
    __shared__ uint4   coefH2[9][10];      // layer2 f16x8
    __shared__ float4  coef6[12];          // layer6 f32: 11 intervals + zero slot
    __shared__ float   sbw[2][18];         // base_w1 / base_w2
    __shared__ float   scw[36], scb[3];    // 1x1 conv
    __shared__ float   sb6;
    __shared__ float   zpart[256][13];     // layer2 partial z, padded stride 13

    const int tid = threadIdx.x;
    const int tx0 = blockIdx.x * TILE;
    const int ty0 = blockIdx.y * TILE;
    const int b   = blockIdx.z;

    // ---- build f16 k-pair-packed spline tables for both conv layers ----
    for (int e = tid; e < 180; e += NT) {
        int l = e / 90, r = e % 90, s = r / 10, si = r % 10;
        const float* sw  = l ? spline_w2 : spline_w1;
        const float* scl = l ? scaler2   : scaler1;
        float4 a = spline_poly(sw + s * 6,       scl[s],     6, si);
        float4 c = spline_poly(sw + (9 + s) * 6, scl[9 + s], 6, si);
        uint4 q;
        q.x = pack_h2(a.x, a.y); q.y = pack_h2(a.z, a.w);
        q.z = pack_h2(c.x, c.y); q.w = pack_h2(c.z, c.w);
        if (l) coefH2[s][si] = q; else coefH1[s][si] = q;
    }
    if (tid < 12) coef6[tid] = spline_poly(spline_w6, scaler6[0], 8, tid);
    if (tid < 18) { sbw[0][tid] = base_w1[tid]; sbw[1][tid] = base_w2[tid]; }
    if (tid < 36) scw[tid] = conv_w[tid];
    if (tid < 3)  scb[tid] = conv_b[tid];
    if (tid == 0) sb6 = base_w6[0];

    // ---- encode x tile + halo2 (zero-padded values ARE transformed, per ref) ----
    for (int i = tid; i < 1200; i += NT) {
        int c = i / 400, r = i % 400, ly = r / 20, lx = r % 20;
        int gy = ty0 - 2 + ly, gx = tx0 - 2 + lx;
        float v = 0.0f;
        if ((unsigned)gy < 256u && (unsigned)gx < 256u)
            v = x[((b * 3 + c) * 256 + gy) * 256 + gx];
        Enc e = kan_enc3(v, -3.0f, 1.5f, 9.0f);
        encXg[i] = make_float2(e.g, e.w);
        encXs[i] = (unsigned short)e.si;
    }
    __syncthreads();

    // ---- layer1 (3ch -> 6ch) on 18x18, encode channel-paired outputs ----
    {
        float rb0[9], rb1[9];
        #pragma unroll
        for (int s = 0; s < 9; ++s) { rb0[s] = sbw[0][s]; rb1[s] = sbw[0][9 + s]; }
        for (int i = tid; i < 972; i += NT) {
            int c = i / 324, r = i % 324, ly = r / 18, lx = r % 18;
            float a0 = 0.0f, a1 = 0.0f;
            int base = c * 400 + ly * 20 + lx;
            #pragma unroll
            for (int s = 0; s < 9; ++s) {
                int p = base + (s / 3) * 20 + (s % 3);
                float2 gw = encXg[p];
                int si = encXs[p];
                uint4 q = coefH1[s][si];
                float w = gw.y, w2 = w * w;
                h2f p1 = __builtin_amdgcn_cvt_pkrtz(1.0f, w);
                h2f p2 = __builtin_amdgcn_cvt_pkrtz(w2, w2 * w);
                a0 += gw.x * rb0[s];
                a1 += gw.x * rb1[s];
                a0 = fdot2(u2h(q.x), p1, a0); a0 = fdot2(u2h(q.y), p2, a0);
                a1 = fdot2(u2h(q.z), p1, a1); a1 = fdot2(u2h(q.w), p2, a1);
            }
            int gy = ty0 - 1 + ly, gx = tx0 - 1 + lx;
            if (!((unsigned)gy < 256u && (unsigned)gx < 256u)) { a0 = 0.0f; a1 = 0.0f; }
            Enc e0 = kan_enc3(a0, -3.0f, 1.5f, 9.0f);
            Enc e1 = kan_enc3(a1, -3.0f, 1.5f, 9.0f);
            encYg[c][r] = make_float4(e0.g, e0.w, e1.g, e1.w);
            encYs[c][r] = make_ushort2((unsigned short)e0.si, (unsigned short)e1.si);
        }
    }
    __syncthreads();

    // ---- layer2 (6 -> 12): one (pixel, channel-pair) per thread ----
    {
        const int pix = tid & 255;
        const int c   = tid >> 8;            // 0..2 (768 = 256*3 exactly)
        const int ly = pix >> 4, lx = pix & 15;
        float rb0[9], rb1[9];
        #pragma unroll
        for (int s = 0; s < 9; ++s) { rb0[s] = sbw[1][s]; rb1[s] = sbw[1][9 + s]; }
        const int rbase = ly * 18 + lx;
        float a00 = 0.0f, a01 = 0.0f, a10 = 0.0f, a11 = 0.0f;
        #pragma unroll
        for (int s = 0; s < 9; ++s) {
            int p = rbase + (s / 3) * 18 + (s % 3);
            float4 e = encYg[c][p];
            ushort2 ss = encYs[c][p];
            uint4 q0 = coefH2[s][ss.x];
            uint4 q1 = coefH2[s][ss.y];
            {   // channel h=0
                float w = e.y, w2 = w * w;
                h2f p1 = __builtin_amdgcn_cvt_pkrtz(1.0f, w);
                h2f p2 = __builtin_amdgcn_cvt_pkrtz(w2, w2 * w);
                a00 += e.x * rb0[s];
                a01 += e.x * rb1[s];
                a00 = fdot2(u2h(q0.x), p1, a00); a00 = fdot2(u2h(q0.y), p2, a00);
                a01 = fdot2(u2h(q0.z), p1, a01); a01 = fdot2(u2h(q0.w), p2, a01);
            }
            {   // channel h=1
                float w = e.w, w2 = w * w;
                h2f p1 = __builtin_amdgcn_cvt_pkrtz(1.0f, w);
                h2f p2 = __builtin_amdgcn_cvt_pkrtz(w2, w2 * w);
                a10 += e.z * rb0[s];
                a11 += e.z * rb1[s];
                a10 = fdot2(u2h(q1.x), p1, a10); a10 = fdot2(u2h(q1.y), p2, a10);
                a11 = fdot2(u2h(q1.z), p1, a11); a11 = fdot2(u2h(q1.w), p2, a11);
            }
        }
        zpart[pix][4 * c + 0] = a00;
        zpart[pix][4 * c + 1] = a01;
        zpart[pix][4 * c + 2] = a10;
        zpart[pix][4 * c + 3] = a11;
    }
    __syncthreads();

    // ---- 1x1 conv (12->3) + pointwise KAN layer6 (f32) + store (threads<256) ----
    if (tid < 256) {
        const int pix = tid;
        const int ly = pix >> 4, lx = pix & 15;
        const int gy = ty0 + ly, gx = tx0 + lx;
        float z[12];
        #pragma unroll
        for (int c = 0; c < 12; ++c) z[c] = zpart[pix][c];
        #pragma unroll
        for (int o = 0; o < 3; ++o) {
            float v = scb[o];
            #pragma unroll
            for (int c = 0; c < 12; ++c) v += scw[o * 12 + c] * z[c];
            Enc t = kan_enc3(v, -2.2f, 2.5f, 11.0f);
            out[((b * 3 + o) * 256 + gy) * 256 + gx] = t.g * sb6 + poly_eval(coef6[t.si], t.w);
        }
    }
}

extern "C" void kernel_launch(void* const* d_in, const int* in_sizes, int n_in,
                              void* d_out, int out_size, void* d_ws, size_t ws_size,
                              hipStream_t stream) {
    (void)in_sizes; (void)n_in; (void)d_ws; (void)ws_size; (void)out_size;
    const float* x         = (const float*)d_in[0];
    const float* base_w1   = (const float*)d_in[1];
    const float* spline_w1 = (const float*)d_in[2];
    const float* scaler1   = (const float*)d_in[3];
    const float* base_w2   = (const float*)d_in[4];
    const float* spline_w2 = (const float*)d_in[5];
    const float* scaler2   = (const float*)d_in[6];
    const float* conv_w    = (const float*)d_in[7];
    const float* conv_b    = (const float*)d_in[8];
    const float* base_w6   = (const float*)d_in[9];
    const float* spline_w6 = (const float*)d_in[10];
    const float* scaler6   = (const float*)d_in[11];
    float* out = (float*)d_out;

    dim3 grid(256 / TILE, 256 / TILE, 4);
    dim3 block(NT);
    ZS_MKAN_72121090834671_kernel<<<grid, block, 0, stream>>>(
        x, base_w1, spline_w1, scaler1, base_w2, spline_w2, scaler2,
        conv_w, conv_b, base_w6, spline_w6, scaler6, out);
}

// Round 15
// 21.283 us; speedup vs baseline: 1.2343x; 1.1278x over previous
//
#include <hip/hip_runtime.h>
#include <hip/hip_fp16.h>

#define TILE 16

typedef __fp16 h2f __attribute__((ext_vector_type(2)));

union H2U { h2f h; unsigned u; __half2 hh; };

__device__ __forceinline__ h2f u2h(unsigned u) { H2U t; t.u = u; return t.h; }

__device__ __forceinline__ unsigned pack_h2(float a, float b) {
    H2U t; t.hh = __halves2half2(__float2half_rn(a), __float2half_rn(b));
    return t.u;
}

// dot2: acc += a.x*b.x + a.y*b.y (f16 mul, f32 acc) — V_DOT2_F32_F16
__device__ __forceinline__ float fdot2(h2f a, h2f b, float acc) {
#if __has_builtin(__builtin_amdgcn_fdot2)
    return __builtin_amdgcn_fdot2(a, b, acc, false);
#else
    return acc + (float)a.x * (float)b.x + (float)a.y * (float)b.y;
#endif
}

// Encode one KAN input: g=silu(v); knot coord T=(v-g0)*invh; w=frac, si=interval
// slot (0 => out-of-span zero slot; 1..tmax => interval floor(T)).
struct Enc { float g, w; int si; };
__device__ __forceinline__ Enc kan_enc3(float v, float g0, float invh, float tmax) {
    Enc e;
    e.g = v / (1.0f + __expf(-v));
    float T = (v - g0) * invh;
    float U = (T >= 0.0f && T < tmax) ? T : -1.0f;
    float mf = floorf(U);
    e.w = U - mf;          // 0 when out of span
    e.si = (int)mf + 1;    // 0 when out of span
    return e;
}

__device__ __forceinline__ float poly_eval(float4 c, float w) {
    return ((c.w * w + c.z) * w + c.y) * w + c.x;
}

// Piecewise-cubic table entry for interval slot si (si=0 zero slot).
__device__ __forceinline__ float4 spline_poly(const float* __restrict__ sw, float sc,
                                              int ncoef, int si) {
    float4 v = make_float4(0.f, 0.f, 0.f, 0.f);
    if (si > 0) {
        int m = si - 1;
        float W[4];
        #pragma unroll
        for (int j = 0; j < 4; ++j) {
            int c = m - 3 + j;
            W[j] = (c >= 0 && c < ncoef) ? sw[c] * sc : 0.0f;
        }
        const float s6 = 1.0f / 6.0f;
        v.x = (W[0] + 4.0f * W[1] + W[2]) * s6;
        v.y = 3.0f * (W[2] - W[0]) * s6;
        v.z = (3.0f * W[0] - 6.0f * W[1] + 3.0f * W[2]) * s6;
        v.w = (W[3] - W[0] + 3.0f * (W[1] - W[2])) * s6;
    }
    return v;
}

__global__ __launch_bounds__(256, 5) void ZS_MKAN_72121090834671_kernel(
    const float* __restrict__ x,
    const float* __restrict__ base_w1, const float* __restrict__ spline_w1,
    const float* __restrict__ scaler1,
    const float* __restrict__ base_w2, const float* __restrict__ spline_w2,
    const float* __restrict__ scaler2,
    const float* __restrict__ conv_w, const float* __restrict__ conv_b,
    const float* __restrict__ base_w6, const float* __restrict__ spline_w6,
    const float* __restrict__ scaler6,
    float* __restrict__ out)
{
    __shared__ float2  encXg[1200];        // (g,w) per x-halo pixel, 3ch x 20x20
    __shared__ unsigned short encXs[1200]; // si per x-halo pixel
    __shared__ float4  encYg[3][324];      // (g0,w0,g1,w1) layer1-out pairs, 18x18
    __shared__ ushort2 encYs[3][324];      // (si0,si1)
    __shared__ uint4   coefH1[9][10];      // layer1 f16x8: k0{c0..c3}, k1{c0..c3}
    __shared__ uint4   coefH2[9][10];      // layer2 f16x8
    __shared__ float4  coef6[12];          // layer6 f32: 11 intervals + zero slot
    __shared__ float   sbw[2][18];         // base_w1 / base_w2
    __shared__ float   scw[36], scb[3];    // 1x1 conv
    __shared__ float   sb6;

    const int tid = threadIdx.x;
    const int tx0 = blockIdx.x * TILE;
    const int ty0 = blockIdx.y * TILE;
    const int b   = blockIdx.z;

    // ---- build f16 k-pair-packed spline tables for both conv layers ----
    for (int e = tid; e < 180; e += 256) {
        int l = e / 90, r = e % 90, s = r / 10, si = r % 10;
        const float* sw  = l ? spline_w2 : spline_w1;
        const float* scl = l ? scaler2   : scaler1;
        float4 a = spline_poly(sw + s * 6,       scl[s],     6, si);
        float4 c = spline_poly(sw + (9 + s) * 6, scl[9 + s], 6, si);
        uint4 q;
        q.x = pack_h2(a.x, a.y); q.y = pack_h2(a.z, a.w);
        q.z = pack_h2(c.x, c.y); q.w = pack_h2(c.z, c.w);
        if (l) coefH2[s][si] = q; else coefH1[s][si] = q;
    }
    if (tid < 12) coef6[tid] = spline_poly(spline_w6, scaler6[0], 8, tid);
    if (tid < 18) { sbw[0][tid] = base_w1[tid]; sbw[1][tid] = base_w2[tid]; }
    if (tid < 36) scw[tid] = conv_w[tid];
    if (tid < 3)  scb[tid] = conv_b[tid];
    if (tid == 0) sb6 = base_w6[0];

    // ---- encode x tile + halo2 (zero-padded values ARE transformed, per ref) ----
    for (int i = tid; i < 1200; i += 256) {
        int c = i / 400, r = i % 400, ly = r / 20, lx = r % 20;
        int gy = ty0 - 2 + ly, gx = tx0 - 2 + lx;
        float v = 0.0f;
        if ((unsigned)gy < 256u && (unsigned)gx < 256u)
            v = x[((b * 3 + c) * 256 + gy) * 256 + gx];
        Enc e = kan_enc3(v, -3.0f, 1.5f, 9.0f);
        encXg[i] = make_float2(e.g, e.w);
        encXs[i] = (unsigned short)e.si;
    }
    __syncthreads();

    // ---- layer1 (3ch -> 6ch) on 18x18, encode channel-paired outputs ----
    {
        float rb0[9], rb1[9];
        #pragma unroll
        for (int s = 0; s < 9; ++s) { rb0[s] = sbw[0][s]; rb1[s] = sbw[0][9 + s]; }
        for (int i = tid; i < 972; i += 256) {
            int c = i / 324, r = i % 324, ly = r / 18, lx = r % 18;
            float a0 = 0.0f, a1 = 0.0f;
            int base = c * 400 + ly * 20 + lx;
            #pragma unroll
            for (int s = 0; s < 9; ++s) {
                int p = base + (s / 3) * 20 + (s % 3);
                float2 gw = encXg[p];
                int si = encXs[p];
                uint4 q = coefH1[s][si];
                float w = gw.y, w2 = w * w;
                h2f p1 = __builtin_amdgcn_cvt_pkrtz(1.0f, w);
                h2f p2 = __builtin_amdgcn_cvt_pkrtz(w2, w2 * w);
                a0 += gw.x * rb0[s];
                a1 += gw.x * rb1[s];
                a0 = fdot2(u2h(q.x), p1, a0); a0 = fdot2(u2h(q.y), p2, a0);
                a1 = fdot2(u2h(q.z), p1, a1); a1 = fdot2(u2h(q.w), p2, a1);
            }
            int gy = ty0 - 1 + ly, gx = tx0 - 1 + lx;
            if (!((unsigned)gy < 256u && (unsigned)gx < 256u)) { a0 = 0.0f; a1 = 0.0f; }
            Enc e0 = kan_enc3(a0, -3.0f, 1.5f, 9.0f);
            Enc e1 = kan_enc3(a1, -3.0f, 1.5f, 9.0f);
            encYg[c][r] = make_float4(e0.g, e0.w, e1.g, e1.w);
            encYs[c][r] = make_ushort2((unsigned short)e0.si, (unsigned short)e1.si);
        }
    }
    __syncthreads();

    // ---- layer2 (6 -> 12) with 1x1 conv folded: 3 running outputs, no z[12] ----
    const int ly = tid >> 4, lx = tid & 15;
    float v0, v1, v2;
    {
        float rb0[9], rb1[9];
        #pragma unroll
        for (int s = 0; s < 9; ++s) { rb0[s] = sbw[1][s]; rb1[s] = sbw[1][9 + s]; }
        v0 = scb[0]; v1 = scb[1]; v2 = scb[2];
        const int rbase = ly * 18 + lx;
        #pragma unroll
        for (int c = 0; c < 3; ++c) {    // pair of y-channels (2c, 2c+1)
            float a00 = 0.0f, a01 = 0.0f, a10 = 0.0f, a11 = 0.0f;
            #pragma unroll
            for (int s = 0; s < 9; ++s) {
                int p = rbase + (s / 3) * 18 + (s % 3);
                float4 e = encYg[c][p];
                ushort2 ss = encYs[c][p];
                uint4 q0 = coefH2[s][ss.x];
                uint4 q1 = coefH2[s][ss.y];
                {   // channel h=0
                    float w = e.y, w2 = w * w;
                    h2f p1 = __builtin_amdgcn_cvt_pkrtz(1.0f, w);
                    h2f p2 = __builtin_amdgcn_cvt_pkrtz(w2, w2 * w);
                    a00 += e.x * rb0[s];
                    a01 += e.x * rb1[s];
                    a00 = fdot2(u2h(q0.x), p1, a00); a00 = fdot2(u2h(q0.y), p2, a00);
                    a01 = fdot2(u2h(q0.z), p1, a01); a01 = fdot2(u2h(q0.w), p2, a01);
                }
                {   // channel h=1
                    float w = e.w, w2 = w * w;
                    h2f p1 = __builtin_amdgcn_cvt_pkrtz(1.0f, w);
                    h2f p2 = __builtin_amdgcn_cvt_pkrtz(w2, w2 * w);
                    a10 += e.z * rb0[s];
                    a11 += e.z * rb1[s];
                    a10 = fdot2(u2h(q1.x), p1, a10); a10 = fdot2(u2h(q1.y), p2, a10);
                    a11 = fdot2(u2h(q1.z), p1, a11); a11 = fdot2(u2h(q1.w), p2, a11);
                }
            }
            // fold 1x1 conv now; z[] never lives past this point
            const int k = 4 * c;
            v0 += scw[k]      * a00 + scw[k + 1]  * a01 + scw[k + 2]  * a10 + scw[k + 3]  * a11;
            v1 += scw[12 + k] * a00 + scw[13 + k] * a01 + scw[14 + k] * a10 + scw[15 + k] * a11;
            v2 += scw[24 + k] * a00 + scw[25 + k] * a01 + scw[26 + k] * a10 + scw[27 + k] * a11;
        }
    }

    // ---- pointwise KAN layer6 (f32) + store ----
    const int gy = ty0 + ly, gx = tx0 + lx;
    float vv[3] = {v0, v1, v2};
    #pragma unroll
    for (int o = 0; o < 3; ++o) {
        Enc t = kan_enc3(vv[o], -2.2f, 2.5f, 11.0f);
        out[((b * 3 + o) * 256 + gy) * 256 + gx] = t.g * sb6 + poly_eval(coef6[t.si], t.w);
    }
}

extern "C" void kernel_launch(void* const* d_in, const int* in_sizes, int n_in,
                              void* d_out, int out_size, void* d_ws, size_t ws_size,
                              hipStream_t stream) {
    (void)in_sizes; (void)n_in; (void)d_ws; (void)ws_size; (void)out_size;
    const float* x         = (const float*)d_in[0];
    const float* base_w1   = (const float*)d_in[1];
    const float* spline_w1 = (const float*)d_in[2];
    const float* scaler1   = (const float*)d_in[3];
    const float* base_w2   = (const float*)d_in[4];
    const float* spline_w2 = (const float*)d_in[5];
    const float* scaler2   = (const float*)d_in[6];
    const float* conv_w    = (const float*)d_in[7];
    const float* conv_b    = (const float*)d_in[8];
    const float* base_w6   = (const float*)d_in[9];
    const float* spline_w6 = (const float*)d_in[10];
    const float* scaler6   = (const float*)d_in[11];
    float* out = (float*)d_out;

    dim3 grid(256 / TILE, 256 / TILE, 4);
    dim3 block(256);
    ZS_MKAN_72121090834671_kernel<<<grid, block, 0, stream>>>(
        x, base_w1, spline_w1, scaler1, base_w2, spline_w2, scaler2,
        conv_w, conv_b, base_w6, spline_w6, scaler6, out);
}